// Round 9
// baseline (234.568 us; speedup 1.0000x reference)
//
#include <hip/hip_runtime.h>

#define LOG2E 1.4426950408889634f

typedef __bf16 bf16x8 __attribute__((ext_vector_type(8)));
typedef float f32x4 __attribute__((ext_vector_type(4)));

__device__ __forceinline__ unsigned short bfb(__bf16 b){
  union { __bf16 b; unsigned short u; } z; z.b = b; return z.u;
}
__device__ __forceinline__ void split8(const float* __restrict__ p, bf16x8& hi, bf16x8& lo){
  #pragma unroll
  for (int j = 0; j < 8; j++){
    float f = p[j];
    __bf16 h = (__bf16)f;
    hi[j] = h;
    lo[j] = (__bf16)(f - (float)h);
  }
}

// ---------------- prep (merged): W2 fold+split, Wv/Wo split, biases, av2 ----------------
// grid (1281, 2):
//   x <  1024: W2 fold+split (y: 0=q, 1=k)
//   1024 <= x < 1280: hi/lo split of Wv (y=0) / Wo (y=1), 262144 elements
//   x == 1280: y==0 -> folded biases; y==1 -> av2g
__global__ __launch_bounds__(256) void prep_all(
    const float* __restrict__ Wq, const float* __restrict__ Aq,
    const float* __restrict__ Wk, const float* __restrict__ Ak,
    const float* __restrict__ bq, const float* __restrict__ bk,
    const float* __restrict__ av,
    const float* __restrict__ Wv, const float* __restrict__ Wo,
    unsigned short* __restrict__ W2q_hi, unsigned short* __restrict__ W2q_lo,
    unsigned short* __restrict__ W2k_hi, unsigned short* __restrict__ W2k_lo,
    unsigned short* __restrict__ Wvh, unsigned short* __restrict__ Wvl,
    unsigned short* __restrict__ Woh, unsigned short* __restrict__ Wol,
    float* __restrict__ b2q, float* __restrict__ b2k, float* __restrict__ av2g){
  if (blockIdx.x >= 1024){
    if (blockIdx.x == 1280){
      if (blockIdx.y == 0){
        #pragma unroll
        for (int rep = 0; rep < 2; rep++){
          int n = rep * 256 + threadIdx.x;
          int h = n >> 6, e = n & 63;
          float aq = 0.f, ak = 0.f;
          for (int c = 0; c < 64; c++){
            aq += Aq[e*64 + c] * bq[h*64 + c];
            ak += Ak[e*64 + c] * bk[h*64 + c];
          }
          b2q[n] = aq * (2.f * LOG2E);
          b2k[n] = ak * (2.f * LOG2E);
        }
      } else {
        if (threadIdx.x < 64) av2g[threadIdx.x] = -2.f * LOG2E * av[threadIdx.x];
      }
      return;
    }
    // split Wv / Wo
    const float* src = blockIdx.y ? Wo : Wv;
    unsigned short* hi = blockIdx.y ? Woh : Wvh;
    unsigned short* lo = blockIdx.y ? Wol : Wvl;
    int base = ((blockIdx.x - 1024) * 256 + threadIdx.x) * 4;
    float4 v = *(const float4*)(src + base);
    ushort4 h, l;
    float f; __bf16 hb;
    f = v.x; hb = (__bf16)f; h.x = bfb(hb); l.x = bfb((__bf16)(f - (float)hb));
    f = v.y; hb = (__bf16)f; h.y = bfb(hb); l.y = bfb((__bf16)(f - (float)hb));
    f = v.z; hb = (__bf16)f; h.z = bfb(hb); l.z = bfb((__bf16)(f - (float)hb));
    f = v.w; hb = (__bf16)f; h.w = bfb(hb); l.w = bfb((__bf16)(f - (float)hb));
    *(ushort4*)(hi + base) = h;
    *(ushort4*)(lo + base) = l;
    return;
  }
  const float* W  = blockIdx.y ? Wk : Wq;
  const float* Am = blockIdx.y ? Ak : Aq;
  unsigned short* WH = blockIdx.y ? W2k_hi : W2q_hi;
  unsigned short* WL = blockIdx.y ? W2k_lo : W2q_lo;
  int idx = blockIdx.x * 256 + threadIdx.x;
  int n = idx >> 9, k = idx & 511;
  int h = n >> 6, e = n & 63;
  float acc = 0.f;
  #pragma unroll 8
  for (int c = 0; c < 64; c++)
    acc += Am[e*64 + c] * W[(h*64 + c)*512 + k];
  float v = acc * (2.f * LOG2E);
  __bf16 hb = (__bf16)v;
  WH[n*512 + k] = bfb(hb);
  WL[n*512 + k] = bfb((__bf16)(v - (float)hb));
}

// ---------------- MFMA GEMM: C[1024][512] = A(fp32) * B^T(pre-split hi/lo) + bias ----------
struct GemmBatch {
  const float* Af;
  const unsigned short *Bh, *Bl;
  const float* bias;
  float* Cf;
  int transposed;                  // 1: qpT layout ((b*8+h)*64+dk)*512 + i
};
struct GemmArgs { GemmBatch g[3]; };

__global__ __launch_bounds__(256) void gemm_nk(GemmArgs ga){
  GemmBatch gb = ga.g[blockIdx.z];
  const int lane = threadIdx.x & 63;
  const int w    = threadIdx.x >> 6;
  const int l15  = lane & 15, quad = lane >> 4;
  const int m  = blockIdx.x * 64 + w * 16 + l15;
  const int nb = blockIdx.y * 64 + l15;
  const float* Arow = gb.Af + (size_t)m * 512;
  f32x4 ac0 = {0.f,0.f,0.f,0.f}, ac1 = ac0, ac2 = ac0, ac3 = ac0;

  #pragma unroll 2
  for (int ks = 0; ks < 16; ks++){
    int ko = ks * 32 + quad * 8;
    bf16x8 ah, al;
    split8(Arow + ko, ah, al);
    #pragma unroll
    for (int t = 0; t < 4; t++){
      bf16x8 bh = *(const bf16x8*)(gb.Bh + (size_t)(nb + t*16) * 512 + ko);
      bf16x8 bl = *(const bf16x8*)(gb.Bl + (size_t)(nb + t*16) * 512 + ko);
      f32x4& ac = (t==0)?ac0:(t==1)?ac1:(t==2)?ac2:ac3;
      ac = __builtin_amdgcn_mfma_f32_16x16x32_bf16(ah, bh, ac, 0, 0, 0);
      ac = __builtin_amdgcn_mfma_f32_16x16x32_bf16(al, bh, ac, 0, 0, 0);
      ac = __builtin_amdgcn_mfma_f32_16x16x32_bf16(ah, bl, ac, 0, 0, 0);
    }
  }

  const int mrow = blockIdx.x * 64 + w * 16 + quad * 4;
  #pragma unroll
  for (int t = 0; t < 4; t++){
    f32x4 v = (t==0)?ac0:(t==1)?ac1:(t==2)?ac2:ac3;
    int n = blockIdx.y * 64 + t * 16 + l15;
    float bs = gb.bias[n];
    #pragma unroll
    for (int r = 0; r < 4; r++){
      float val = v[r] + bs;
      int m2 = mrow + r;
      if (gb.transposed){
        gb.Cf[(size_t)(((m2 >> 9) * 8 + (n >> 6)) * 64 + (n & 63)) * 512 + (m2 & 511)] = val;
      } else {
        gb.Cf[(size_t)m2 * 512 + n] = val;
      }
    }
  }
}

// ---------------- fused additive-attention core (8-row blocks, 64-j chunks, dbuf) ----------
// grid (64,16): x = 8-row query block, y = bh. 256 thr = 4 waves. 4 blocks/CU.
// bufA = K chunk [d][j] stride 66, bufB = V chunk. 8 chunks of 64 j.
// X: V_c->regs, score from bufA (1 j/lane, 2 rows/wave), publish P hi/lo, V->bufB.
// Y: K_{c+1}->regs, PV MFMA (m=16, rows 8-15 zero), K->bufA.
__global__ __launch_bounds__(256, 4) void attn_kernel(
    const float* __restrict__ qpT, const float* __restrict__ kp,
    const float* __restrict__ Vv, const float* __restrict__ av2g,
    float* __restrict__ Oh){
  __shared__ float bufA[64 * 66];
  __shared__ float bufB[64 * 66];
  __shared__ unsigned short pcb[2 * 16 * 72];   // P hi/lo [16][72], rows 8-15 stay zero
  __shared__ float dn[8];

  const int tid = threadIdx.x, lane = tid & 63, w = tid >> 6;
  const int l15 = lane & 15, quad = lane >> 4;
  const int bh = blockIdx.y;
  const int i0 = blockIdx.x * 8;
  const size_t kbase = (size_t)(bh >> 3) * 512 * 512 + (size_t)(bh & 7) * 64;
  const int r0 = __builtin_amdgcn_readfirstlane(2 * w);    // rows 2w, 2w+1
  const size_t qbase = (size_t)bh * 64 * 512 + i0 + r0;
  const int ntile = w;                                     // 16-d tile per wave

  // zero P pad rows 8..15 (hi+lo)
  for (int t = tid; t < 2 * 8 * 72; t += 256){
    int buf = t / (8 * 72), rem = t - buf * 8 * 72;
    pcb[(buf * 16 + 8 + rem / 72) * 72 + (rem % 72)] = 0;
  }
  { // stage K_0 -> bufA (lane = d, 16 j per wave)
    #pragma unroll
    for (int m = 0; m < 16; m++){
      int j = w + 4 * m;
      bufA[lane * 66 + j] = kp[kbase + (size_t)j * 512 + lane];
    }
  }
  float den0 = 0.f, den1 = 0.f;
  f32x4 Cacc = {0.f, 0.f, 0.f, 0.f};
  __syncthreads();

  for (int c = 0; c < 8; c++){
    // ---- X: V_c -> regs, score from bufA, publish P, V -> bufB ----
    float vreg[16];
    #pragma unroll
    for (int m = 0; m < 16; m++){
      int j = w + 4 * m;
      vreg[m] = Vv[kbase + (size_t)(c*64 + j) * 512 + lane];
    }
    float s0 = 0.f, s1 = 0.f;
    #pragma unroll 8
    for (int d = 0; d < 64; d++){
      float2 qv = *(const float2*)(qpT + qbase + (size_t)d * 512);  // wave-uniform
      float a2 = av2g[d];                                           // wave-uniform
      float kk = bufA[d * 66 + lane];
      s0 += a2 * __builtin_amdgcn_rcpf(1.f + __builtin_amdgcn_exp2f(qv.x + kk));
      s1 += a2 * __builtin_amdgcn_rcpf(1.f + __builtin_amdgcn_exp2f(qv.y + kk));
    }
    float e0 = __builtin_amdgcn_exp2f(s0);
    float e1 = __builtin_amdgcn_exp2f(s1);
    den0 += e0; den1 += e1;
    {
      __bf16 h0 = (__bf16)e0, h1 = (__bf16)e1;
      pcb[(0*16 + r0    ) * 72 + lane] = bfb(h0);
      pcb[(0*16 + r0 + 1) * 72 + lane] = bfb(h1);
      pcb[(1*16 + r0    ) * 72 + lane] = bfb((__bf16)(e0 - (float)h0));
      pcb[(1*16 + r0 + 1) * 72 + lane] = bfb((__bf16)(e1 - (float)h1));
    }
    #pragma unroll
    for (int m = 0; m < 16; m++){
      int j = w + 4 * m;
      bufB[lane * 66 + j] = vreg[m];
    }
    __syncthreads();

    // ---- Y: K_{c+1} -> regs, PV MFMA from bufB/pcb, K -> bufA ----
    float kreg[16];
    if (c < 7){
      #pragma unroll
      for (int m = 0; m < 16; m++){
        int j = w + 4 * m;
        kreg[m] = kp[kbase + (size_t)((c+1)*64 + j) * 512 + lane];
      }
    }
    #pragma unroll
    for (int kk2 = 0; kk2 < 2; kk2++){
      int k0 = kk2 * 32 + quad * 8;
      bf16x8 ph = *(const bf16x8*)&pcb[(0*16 + l15) * 72 + k0];
      bf16x8 pl = *(const bf16x8*)&pcb[(1*16 + l15) * 72 + k0];
      const float* vp = &bufB[(ntile*16 + l15) * 66 + k0];
      bf16x8 vh, vl;
      #pragma unroll
      for (int j = 0; j < 8; j++){
        float f = vp[j];
        __bf16 h = (__bf16)f;
        vh[j] = h; vl[j] = (__bf16)(f - (float)h);
      }
      Cacc = __builtin_amdgcn_mfma_f32_16x16x32_bf16(ph, vh, Cacc, 0, 0, 0);
      Cacc = __builtin_amdgcn_mfma_f32_16x16x32_bf16(pl, vh, Cacc, 0, 0, 0);
      Cacc = __builtin_amdgcn_mfma_f32_16x16x32_bf16(ph, vl, Cacc, 0, 0, 0);
    }
    if (c < 7){
      #pragma unroll
      for (int m = 0; m < 16; m++){
        int j = w + 4 * m;
        bufA[lane * 66 + j] = kreg[m];
      }
    }
    __syncthreads();
  }

  // den reduction: wave w owns rows 2w, 2w+1
  #pragma unroll
  for (int off = 1; off < 64; off <<= 1){
    den0 += __shfl_xor(den0, off, 64);
    den1 += __shfl_xor(den1, off, 64);
  }
  if (lane == 0){ dn[r0] = den0; dn[r0 + 1] = den1; }
  __syncthreads();
  if (quad < 2){   // C/D rows 0..7 are the real P rows
    #pragma unroll
    for (int r = 0; r < 4; r++){
      int row = quad * 4 + r;
      Oh[kbase + (size_t)(i0 + row) * 512 + ntile * 16 + l15] = Cacc[r] / dn[row];
    }
  }
}

// ---------------- launch ----------------
extern "C" void kernel_launch(void* const* d_in, const int* in_sizes, int n_in,
                              void* d_out, int out_size, void* d_ws, size_t ws_size,
                              hipStream_t stream){
  const float* q_in = (const float*)d_in[0];
  const float* k_in = (const float*)d_in[1];
  const float* v_in = (const float*)d_in[2];
  const float* Wq_  = (const float*)d_in[3];
  const float* bq_  = (const float*)d_in[4];
  const float* Wk_  = (const float*)d_in[5];
  const float* bk_  = (const float*)d_in[6];
  const float* Wv_  = (const float*)d_in[7];
  const float* bv_  = (const float*)d_in[8];
  const float* Wo_  = (const float*)d_in[9];
  const float* bo_  = (const float*)d_in[10];
  const float* Aq_  = (const float*)d_in[11];
  const float* Ak_  = (const float*)d_in[12];
  const float* av_  = (const float*)d_in[13];

  char* ws = (char*)d_ws;
  unsigned short* W2q_hi = (unsigned short*)(ws + 0);
  unsigned short* W2q_lo = (unsigned short*)(ws + 524288);
  unsigned short* W2k_hi = (unsigned short*)(ws + 1048576);
  unsigned short* W2k_lo = (unsigned short*)(ws + 1572864);
  float* Oh = (float*)(ws + 0);
  unsigned short* Wvh = (unsigned short*)(ws + 2097152);
  unsigned short* Wvl = (unsigned short*)(ws + 2621440);
  unsigned short* Woh = (unsigned short*)(ws + 3145728);
  unsigned short* Wol = (unsigned short*)(ws + 3670016);
  float* b2q  = (float*)(ws + 4194304);
  float* b2k  = (float*)(ws + 4196352);
  float* av2g = (float*)(ws + 4198400);
  float* qpT  = (float*)(ws + 4198656);
  float* kp   = (float*)(ws + 6295808);
  float* Vw   = (float*)(ws + 8392960);

  prep_all<<<dim3(1281, 2, 1), 256, 0, stream>>>(Wq_, Aq_, Wk_, Ak_, bq_, bk_, av_,
                                                 Wv_, Wo_,
                                                 W2q_hi, W2q_lo, W2k_hi, W2k_lo,
                                                 Wvh, Wvl, Woh, Wol,
                                                 b2q, b2k, av2g);

  GemmArgs ga;
  ga.g[0] = { q_in, W2q_hi, W2q_lo, b2q, qpT, 1 };
  ga.g[1] = { k_in, W2k_hi, W2k_lo, b2k, kp,  0 };
  ga.g[2] = { v_in, Wvh,    Wvl,    bv_, Vw,  0 };
  gemm_nk<<<dim3(16, 8, 3), 256, 0, stream>>>(ga);

  attn_kernel<<<dim3(64, 16, 1), 256, 0, stream>>>(qpT, kp, Vw, av2g, Oh);

  GemmArgs go;
  go.g[0] = { Oh, Woh, Wol, bo_, (float*)d_out, 0 };
  go.g[1] = go.g[0];
  go.g[2] = go.g[0];
  gemm_nk<<<dim3(16, 8, 1), 256, 0, stream>>>(go);
}